// Round 1
// baseline (857.982 us; speedup 1.0000x reference)
//
#include <hip/hip_runtime.h>

#define B_ 2
#define S_ 2048
#define HID_ 768
#define NH_ 12
#define HD_ 64

typedef unsigned short u16;
typedef __attribute__((ext_vector_type(8))) short bf16x8;
typedef __attribute__((ext_vector_type(4))) float f32x4;

static __device__ inline u16 f2bf(float f) {
    union { float f; unsigned u; } v; v.f = f;
    unsigned r = v.u + 0x7fffu + ((v.u >> 16) & 1u);
    return (u16)(r >> 16);
}

// ---------------- cast fp32 -> bf16, 4 elems/thread ----------------
__global__ void cast_bf16(const float* __restrict__ src, u16* __restrict__ dst, int n) {
    int i = (blockIdx.x * blockDim.x + threadIdx.x) * 4;
    if (i < n) {
        float4 v = *(const float4*)(src + i);
        unsigned lo = (unsigned)f2bf(v.x) | ((unsigned)f2bf(v.y) << 16);
        unsigned hi = (unsigned)f2bf(v.z) | ((unsigned)f2bf(v.w) << 16);
        uint2 o; o.x = lo; o.y = hi;
        *(uint2*)(dst + i) = o;
    }
}

// ---------------- QKV projection GEMM ----------------
// out[m][n] = sum_k hs[m][k] * Wcat[n][k]  (+bias), M=4096, N=2304, K=768
// 64x64 tile per block, 4 waves, each wave 16 rows x 64 cols.
__global__ __launch_bounds__(256) void qkv_gemm(
    const u16* __restrict__ hsb, const u16* __restrict__ wcat,
    const float* __restrict__ bq, const float* __restrict__ bk, const float* __restrict__ bv,
    u16* __restrict__ Qg, u16* __restrict__ Kg, u16* __restrict__ Vtg)
{
    __shared__ u16 As[64 * 40];
    __shared__ u16 Bs[64 * 40];
    __shared__ u16 Vs[64 * 72];

    const int m0 = blockIdx.x * 64;
    const int n0 = blockIdx.y * 64;
    const int tid = threadIdx.x;
    const int wave = tid >> 6, lane = tid & 63;
    const int l = lane & 15, quad = lane >> 4;

    f32x4 acc[4];
#pragma unroll
    for (int t = 0; t < 4; t++) acc[t] = (f32x4){0.f, 0.f, 0.f, 0.f};

    const int srow = tid >> 2;          // 0..63
    const int skg = (tid & 3) * 8;      // 0,8,16,24

    for (int k0 = 0; k0 < HID_; k0 += 32) {
        *(int4*)(&As[srow * 40 + skg]) = *(const int4*)(&hsb[(size_t)(m0 + srow) * HID_ + k0 + skg]);
        *(int4*)(&Bs[srow * 40 + skg]) = *(const int4*)(&wcat[(size_t)(n0 + srow) * HID_ + k0 + skg]);
        __syncthreads();
        bf16x8 a = *(const bf16x8*)(&As[(wave * 16 + l) * 40 + quad * 8]);
#pragma unroll
        for (int t = 0; t < 4; t++) {
            bf16x8 b = *(const bf16x8*)(&Bs[(t * 16 + l) * 40 + quad * 8]);
            acc[t] = __builtin_amdgcn_mfma_f32_16x16x32_bf16(a, b, acc[t], 0, 0, 0);
        }
        __syncthreads();
    }

    // epilogue: whole block is one (proj, head)
    const int proj = n0 / HID_;             // 0=Q 1=K 2=V
    const int cbase = n0 - proj * HID_;     // multiple of 64
    const int h = cbase >> 6;
    const int bidx = m0 >> 11;
    const int srow0 = m0 & (S_ - 1);
    const float* bias = (proj == 0) ? bq : ((proj == 1) ? bk : bv);

    if (proj < 2) {
        u16* dst = (proj == 0) ? Qg : Kg;
        const float sc = (proj == 0) ? 0.125f : 1.0f;
#pragma unroll
        for (int t = 0; t < 4; t++) {
            const int d = t * 16 + l;
            const float bb = bias[cbase + d];
#pragma unroll
            for (int rr = 0; rr < 4; rr++) {
                int s = srow0 + wave * 16 + quad * 4 + rr;
                float v = (acc[t][rr] + bb) * sc;
                dst[(((size_t)bidx * NH_ + h) * S_ + s) * HD_ + d] = f2bf(v);
            }
        }
    } else {
        // V: transpose through LDS, write Vt[b][h][d][s] coalesced
#pragma unroll
        for (int t = 0; t < 4; t++) {
            const int d = t * 16 + l;
            const float bb = bias[cbase + d];
#pragma unroll
            for (int rr = 0; rr < 4; rr++) {
                int sl = wave * 16 + quad * 4 + rr;
                Vs[d * 72 + sl] = f2bf(acc[t][rr] + bb);
            }
        }
        __syncthreads();
        const int drow = tid >> 2;           // d 0..63
        const int sseg = (tid & 3) * 16;     // s segment
        size_t base = (((size_t)bidx * NH_ + h) * HD_ + drow) * S_ + srow0 + sseg;
        *(int4*)(&Vtg[base])     = *(const int4*)(&Vs[drow * 72 + sseg]);
        *(int4*)(&Vtg[base + 8]) = *(const int4*)(&Vs[drow * 72 + sseg + 8]);
    }
}

// ---------------- fused flash attention ----------------
// grid: (S/64, NH, B), 256 threads = 4 waves, each wave owns 16 q-rows.
__global__ __launch_bounds__(256) void attn(
    const u16* __restrict__ Qg, const u16* __restrict__ Kg, const u16* __restrict__ Vtg,
    const float* __restrict__ rel, const float* __restrict__ rel2,
    const int* __restrict__ mask, float* __restrict__ out)
{
    __shared__ u16 Ks[64 * 72];
    __shared__ u16 Vts[64 * 72];
    __shared__ u16 Ps[4 * 16 * 72];

    const int q0 = blockIdx.x * 64;
    const int h = blockIdx.y;
    const int b = blockIdx.z;
    const int tid = threadIdx.x;
    const int wave = tid >> 6, lane = tid & 63;
    const int l = lane & 15, quad = lane >> 4;
    const int bh = b * NH_ + h;

    // Q fragments stay in registers for the whole kernel
    bf16x8 qf[2];
    {
        const int qrow = q0 + wave * 16 + l;
        qf[0] = *(const bf16x8*)(&Qg[((size_t)bh * S_ + qrow) * HD_ + quad * 8]);
        qf[1] = *(const bf16x8*)(&Qg[((size_t)bh * S_ + qrow) * HD_ + 32 + quad * 8]);
    }

    f32x4 o[4];
#pragma unroll
    for (int t = 0; t < 4; t++) o[t] = (f32x4){0.f, 0.f, 0.f, 0.f};
    float m_run[4], l_run[4];
#pragma unroll
    for (int rr = 0; rr < 4; rr++) { m_run[rr] = -3.4028234663852886e38f; l_run[rr] = 0.f; }

    const int srow = tid >> 2;        // 0..63
    const int sseg = (tid & 3) * 8;   // 0,8,16,24

    const size_t relbase = (size_t)bh * S_ * S_;
    const size_t mbase = (size_t)b * S_ * S_;

    for (int k0 = 0; k0 < S_; k0 += 64) {
        // stage K chunk [key][d] and Vt chunk [d][key]
        {
            size_t kg = ((size_t)bh * S_ + k0 + srow) * HD_;
            *(int4*)(&Ks[srow * 72 + sseg])      = *(const int4*)(&Kg[kg + sseg]);
            *(int4*)(&Ks[srow * 72 + 32 + sseg]) = *(const int4*)(&Kg[kg + 32 + sseg]);
            size_t vg = ((size_t)bh * HD_ + srow) * S_ + k0;
            *(int4*)(&Vts[srow * 72 + sseg])      = *(const int4*)(&Vtg[vg + sseg]);
            *(int4*)(&Vts[srow * 72 + 32 + sseg]) = *(const int4*)(&Vtg[vg + 32 + sseg]);
        }
        __syncthreads();

        // scores: acc init = rel + rel2 (C/D layout), then QK^T MFMA, then mask
        f32x4 sacc[4];
#pragma unroll
        for (int t = 0; t < 4; t++) {
            const int col = k0 + t * 16 + l;
#pragma unroll
            for (int rr = 0; rr < 4; rr++) {
                const int row = q0 + wave * 16 + quad * 4 + rr;
                sacc[t][rr] = rel[relbase + (size_t)row * S_ + col] +
                              rel2[relbase + (size_t)row * S_ + col];
            }
            bf16x8 b0 = *(const bf16x8*)(&Ks[(t * 16 + l) * 72 + quad * 8]);
            sacc[t] = __builtin_amdgcn_mfma_f32_16x16x32_bf16(qf[0], b0, sacc[t], 0, 0, 0);
            bf16x8 b1 = *(const bf16x8*)(&Ks[(t * 16 + l) * 72 + 32 + quad * 8]);
            sacc[t] = __builtin_amdgcn_mfma_f32_16x16x32_bf16(qf[1], b1, sacc[t], 0, 0, 0);
#pragma unroll
            for (int rr = 0; rr < 4; rr++) {
                const int row = q0 + wave * 16 + quad * 4 + rr;
                if (mask[mbase + (size_t)row * S_ + col])
                    sacc[t][rr] = -3.4028234663852886e38f;
            }
        }

        // online softmax, per q-row (rows live in quad-groups of 16 lanes)
#pragma unroll
        for (int rr = 0; rr < 4; rr++) {
            float mx = fmaxf(fmaxf(sacc[0][rr], sacc[1][rr]), fmaxf(sacc[2][rr], sacc[3][rr]));
#pragma unroll
            for (int off = 1; off < 16; off <<= 1) mx = fmaxf(mx, __shfl_xor(mx, off, 64));
            float mnew = fmaxf(m_run[rr], mx);
            float alpha = __expf(m_run[rr] - mnew);
            float rs = 0.f;
#pragma unroll
            for (int t = 0; t < 4; t++) {
                float p = __expf(sacc[t][rr] - mnew);
                sacc[t][rr] = p;
                rs += p;
            }
#pragma unroll
            for (int off = 1; off < 16; off <<= 1) rs += __shfl_xor(rs, off, 64);
            l_run[rr] = l_run[rr] * alpha + rs;
            m_run[rr] = mnew;
#pragma unroll
            for (int dt = 0; dt < 4; dt++) o[dt][rr] *= alpha;
        }

        // write P (bf16) to LDS in [row][t] so it can be read as A-fragments
#pragma unroll
        for (int t = 0; t < 4; t++)
#pragma unroll
            for (int rr = 0; rr < 4; rr++)
                Ps[(wave * 16 + quad * 4 + rr) * 72 + t * 16 + l] = f2bf(sacc[t][rr]);
        __syncthreads();

        // PV: O += P * V
        bf16x8 pa0 = *(const bf16x8*)(&Ps[(wave * 16 + l) * 72 + quad * 8]);
        bf16x8 pa1 = *(const bf16x8*)(&Ps[(wave * 16 + l) * 72 + 32 + quad * 8]);
#pragma unroll
        for (int dt = 0; dt < 4; dt++) {
            bf16x8 v0 = *(const bf16x8*)(&Vts[(dt * 16 + l) * 72 + quad * 8]);
            o[dt] = __builtin_amdgcn_mfma_f32_16x16x32_bf16(pa0, v0, o[dt], 0, 0, 0);
            bf16x8 v1 = *(const bf16x8*)(&Vts[(dt * 16 + l) * 72 + 32 + quad * 8]);
            o[dt] = __builtin_amdgcn_mfma_f32_16x16x32_bf16(pa1, v1, o[dt], 0, 0, 0);
        }
        __syncthreads();
    }

    // epilogue: out[b][s][h*64+d] = O / l
#pragma unroll
    for (int dt = 0; dt < 4; dt++) {
#pragma unroll
        for (int rr = 0; rr < 4; rr++) {
            const int row = q0 + wave * 16 + quad * 4 + rr;
            out[((size_t)b * S_ + row) * HID_ + h * HD_ + dt * 16 + l] = o[dt][rr] / l_run[rr];
        }
    }
}

extern "C" void kernel_launch(void* const* d_in, const int* in_sizes, int n_in,
                              void* d_out, int out_size, void* d_ws, size_t ws_size,
                              hipStream_t stream) {
    const float* hs   = (const float*)d_in[0];
    const float* rel  = (const float*)d_in[1];
    const float* rel2 = (const float*)d_in[2];
    const int*   mask = (const int*)d_in[3];
    const float* Wq = (const float*)d_in[4];
    const float* bq = (const float*)d_in[5];
    const float* Wk = (const float*)d_in[6];
    const float* bk = (const float*)d_in[7];
    const float* Wv = (const float*)d_in[8];
    const float* bv = (const float*)d_in[9];
    float* out = (float*)d_out;

    char* ws = (char*)d_ws;
    u16* hsb  = (u16*)(ws);                      // 4096*768   bf16 = 6291456 B
    u16* wcat = (u16*)(ws + 6291456);            // 2304*768   bf16 = 3538944 B
    u16* Qg   = (u16*)(ws + 9830400);            // [B][NH][S][HD] bf16 = 6291456 B
    u16* Kg   = (u16*)(ws + 16121856);           // same
    u16* Vtg  = (u16*)(ws + 22413312);           // [B][NH][HD][S] bf16

    // casts
    cast_bf16<<<3072, 256, 0, stream>>>(hs, hsb, B_ * S_ * HID_);
    cast_bf16<<<576, 256, 0, stream>>>(Wq, wcat,             HID_ * HID_);
    cast_bf16<<<576, 256, 0, stream>>>(Wk, wcat + HID_ * HID_,     HID_ * HID_);
    cast_bf16<<<576, 256, 0, stream>>>(Wv, wcat + 2 * HID_ * HID_, HID_ * HID_);

    // QKV projections
    qkv_gemm<<<dim3(64, 36), 256, 0, stream>>>(hsb, wcat, bq, bk, bv, Qg, Kg, Vtg);

    // fused attention
    attn<<<dim3(S_ / 64, NH_, B_), 256, 0, stream>>>(Qg, Kg, Vtg, rel, rel2, mask, out);
}